// Round 15
// baseline (142.783 us; speedup 1.0000x reference)
//
#include <hip/hip_runtime.h>
#include <math.h>

#define BB 8
#define TXT_T 200
#define MEL_T 800
#define N_MEL 80
#define NTHR 192         // 3 waves; window e = 4*tid+k covers [0,771) >= e*max 700
#define CSTR 1024        // padded floats per lpT row; [800,1024) = 0.0f
#define LOG2E 1.44269504088896340736f
#define LN2   0.69314718055994530942f
#define EPS2  (1e-7f * LOG2E)      // eps baked into lpT (log2 domain)
#define NPAD  -1.0e12f

__device__ __forceinline__ float exp2_hw(float x) {
#if __has_builtin(__builtin_amdgcn_exp2f)
    return __builtin_amdgcn_exp2f(x);
#else
    return __expf(LN2 * x);
#endif
}

// log2-domain logsumexp2: log2(2^A + 2^B)
__device__ __forceinline__ float lse2(float A, float B) {
    float m = fmaxf(A, B);
    float e = exp2_hw(-fabsf(A - B));
    return m + __log2f(1.0f + e);
}

// row-local shift-right by D within 16-lane DPP rows; out-of-range lanes get
// `old` (the identity) -- full-rate VALU, no lgkm round-trip.
template <int D>
__device__ __forceinline__ float dpp_shr(float v, float old) {
#if __has_builtin(__builtin_amdgcn_update_dpp)
    return __int_as_float(__builtin_amdgcn_update_dpp(
        __float_as_int(old), __float_as_int(v), 0x110 | D, 0xF, 0xF, false));
#else
    float t = __shfl_up(v, D);
    return ((threadIdx.x & 15) < D) ? old : t;
#endif
}

// Kernel 1: lp[b,j,m] = -0.5/80 * ( sum_n (x-mu)^2*exp(-lv) + sum_n lv )
// natural lp -> d_out+1; log2-domain lp*log2e+eps2 -> lpT [b][j][t] with
// stride CSTR and zero pad [800,1024) (pad cells sit at e>e*, never gathered).
__global__ void __launch_bounds__(256) lp_kernel(
        const float* __restrict__ mu_logvar,   // [B][TXT_T][160]
        const float* __restrict__ melspec,     // [B][N_MEL][MEL_T]
        float* __restrict__ out_lp,            // -> d_out + 1
        float* __restrict__ lpT) {
    const int bt = blockIdx.x;            // b*TXT_T + j
    const int b  = bt / TXT_T;
    const int tid = threadIdx.x;

    __shared__ float s_mu[N_MEL];
    __shared__ float s_ev[N_MEL];
    __shared__ float s_lv[N_MEL];
    __shared__ float s_sumlv;

    if (tid < N_MEL) {
        float mu = mu_logvar[(size_t)bt * (2 * N_MEL) + tid];
        float lv = mu_logvar[(size_t)bt * (2 * N_MEL) + N_MEL + tid];
        s_mu[tid] = mu;
        s_ev[tid] = __expf(-lv);
        s_lv[tid] = lv;
    }
    __syncthreads();
    if (tid == 0) {
        float s = 0.f;
        #pragma unroll
        for (int n = 0; n < N_MEL; ++n) s += s_lv[n];
        s_sumlv = s;
    }
    __syncthreads();

    if (tid < MEL_T / 4) {
        const float4* ms4 = (const float4*)(melspec + (size_t)b * N_MEL * MEL_T);
        float ax = 0.f, ay = 0.f, az = 0.f, aw = 0.f;
        #pragma unroll 8
        for (int n = 0; n < N_MEL; ++n) {
            float4 x = ms4[(size_t)n * (MEL_T / 4) + tid];
            float mu = s_mu[n];
            float ev = s_ev[n];
            float d0 = x.x - mu; ax += d0 * d0 * ev;
            float d1 = x.y - mu; ay += d1 * d1 * ev;
            float d2 = x.z - mu; az += d2 * d2 * ev;
            float d3 = x.w - mu; aw += d3 * d3 * ev;
        }
        const float c = -0.5f / (float)N_MEL;
        float slv = s_sumlv;
        float l0 = c * (ax + slv);
        float l1 = c * (ay + slv);
        float l2 = c * (az + slv);
        float l3 = c * (aw + slv);

        size_t ob = (size_t)bt * MEL_T + tid * 4;
        out_lp[ob + 0] = l0;
        out_lp[ob + 1] = l1;
        out_lp[ob + 2] = l2;
        out_lp[ob + 3] = l3;

        float4 v;
        v.x = l0 * LOG2E + EPS2;
        v.y = l1 * LOG2E + EPS2;
        v.z = l2 * LOG2E + EPS2;
        v.w = l3 * LOG2E + EPS2;
        *(float4*)(lpT + (size_t)bt * CSTR + tid * 4) = v;
    } else {
        float4 zz; zz.x = 0.f; zz.y = 0.f; zz.z = 0.f; zz.w = 0.f;
        *(float4*)(lpT + (size_t)bt * CSTR + 800 + (tid - 200) * 4) = zz;
    }
}

// async-stage one column row slice (wave w: 1024B) global -> LDS. Hazard-free
// (DMA to LDS; no VGPR destination -> no register race with manual vmcnt).
// row = cb + jn*CSTR + (jn & ~3): 16B-aligned; slot s holds element (jn&~3)+s.
__device__ __forceinline__ void stage_col(const float* row, float* sb,
                                          int w, int lane) {
    __builtin_amdgcn_global_load_lds(
        (const __attribute__((address_space(1))) void*)(row + w * 256 + lane * 4),
        (__attribute__((address_space(3))) void*)(sb + w * 256),
        16, 0, 0);
}

// Kernel 2: column scan, diagonal window e = t - j (4 elems/thread), serial
// over txt columns (<=200, avg 150). Per column: same-k v from registers,
// affine (lse,+) prefix: local tree -> 4 DPP rounds -> cross-row fixup ->
// cross-wave fixup. Columns staged to double-buffered LDS via
// global_load_lds (1 inst/wave/col, counted vmcnt(1), 2 cols in flight).
// Algebra identical to the verified 103.6us kernel; only the memory path
// changed (plain loads -> LDS staging).
__global__ void __launch_bounds__(NTHR) scan_kernel(
        const float* __restrict__ lpT,          // [B][TXT_T][CSTR], log2-dom
        const int* __restrict__ text_lengths,
        const int* __restrict__ mel_lengths,
        float* __restrict__ alpha_out) {        // [B]
    __shared__ float sbuf[2][784];              // 768 staged + 16 zero tail
    __shared__ float tot[2][4][2];              // [par][wave][{a,b}]
    const int b = blockIdx.x;
    const int tid = threadIdx.x;
    const int w = tid >> 6;
    const int lane = tid & 63;

    const int melL1 = mel_lengths[b] - 1;       // in [399, 799]
    const int txtL1 = text_lengths[b] - 1;      // in [99, 199]
    const float scale = LN2 / (float)(melL1 + 1);
    const int estar = melL1 - txtL1;            // gather offset, [200, 700]
    const int gtid = estar >> 2;                // in [50, 175] < NTHR
    const int gk = estar & 3;

    const float* cb = lpT + (size_t)b * TXT_T * CSTR;

    // zero the unstaged LDS tail once (slots [768, 784))
    if (tid < 16) { sbuf[0][768 + tid] = 0.0f; sbuf[1][768 + tid] = 0.0f; }
    asm volatile("s_waitcnt lgkmcnt(0)" ::: "memory");

    // A_k = previous column's value at e = 4*tid+k.
    // Col-0 seed: be0(tid0) = lp'(0,0) + A0 = a(0,0) requires A0 = -EPS2.
    float A0 = (tid == 0) ? -EPS2 : NPAD;
    float A1 = NPAD, A2 = NPAD, A3 = NPAD;

    // prologue: stage col 0 and col 1 (txtL1 >= 99 so col 1 exists)
    stage_col(cb, &sbuf[0][0], w, lane);
    stage_col(cb + (size_t)1 * CSTR + 0, &sbuf[1][0], w, lane);  // 1 & ~3 = 0

    int par = 0;
    for (int j = 0; j <= txtL1; ++j) {
        // own col-j slice landed (col j+1 may stay in flight), then make all
        // waves' slices visible.
        asm volatile("s_waitcnt vmcnt(1)" ::: "memory");
        __builtin_amdgcn_sched_barrier(0);
        asm volatile("s_barrier" ::: "memory");

        const float* sb = &sbuf[par][0];
        const int off = (j & 3) + 4 * tid;      // slot of element e = 4*tid
        float al0 = sb[off + 0];
        float al1 = sb[off + 1];
        float al2 = sb[off + 2];
        float al3 = sb[off + 3];

        // affine pairs; v_e = A_e (same offset, pure register pass-through)
        float be0 = al0 + A0;
        float be1 = al1 + A1;
        float be2 = al2 + A2;
        float be3 = al3 + A3;

        // local inclusive tree (depth 2)
        float I0a = al0,        I0b = be0;
        float I1a = al1 + I0a,  I1b = lse2(al1 + I0b, be1);
        float t23a = al3 + al2, t23b = lse2(al3 + be2, be3);
        float I2a = al2 + I1a,  I2b = lse2(al2 + I1b, be2);
        float I3a = t23a + I1a, I3b = lse2(t23a + I1b, t23b);

        // segmented inclusive scan within 16-lane rows via DPP
        float Ta = I3a, Tb = I3b;
        {
            float ia, ib;
            ia = dpp_shr<1>(Ta, 0.0f); ib = dpp_shr<1>(Tb, NPAD);
            Tb = lse2(Ta + ib, Tb); Ta = Ta + ia;
            ia = dpp_shr<2>(Ta, 0.0f); ib = dpp_shr<2>(Tb, NPAD);
            Tb = lse2(Ta + ib, Tb); Ta = Ta + ia;
            ia = dpp_shr<4>(Ta, 0.0f); ib = dpp_shr<4>(Tb, NPAD);
            Tb = lse2(Ta + ib, Tb); Ta = Ta + ia;
            ia = dpp_shr<8>(Ta, 0.0f); ib = dpp_shr<8>(Tb, NPAD);
            Tb = lse2(Ta + ib, Tb); Ta = Ta + ia;
        }

        // cross-row fixup: compose totals of rows < my row
        float t0a = __shfl(Ta, 15), t0b = __shfl(Tb, 15);
        float t1a = __shfl(Ta, 31), t1b = __shfl(Tb, 31);
        float t2a = __shfl(Ta, 47), t2b = __shfl(Tb, 47);
        float c2a = t1a + t0a, c2b = lse2(t1a + t0b, t1b);
        float c3a = t2a + c2a, c3b = lse2(t2a + c2b, t2b);
        int row_ = lane >> 4;
        float Xa = 0.0f, Xb = NPAD;
        if (row_ == 1) { Xa = t0a; Xb = t0b; }
        if (row_ == 2) { Xa = c2a; Xb = c2b; }
        if (row_ == 3) { Xa = c3a; Xb = c3b; }
        float Fa = Ta + Xa;
        float Fb = lse2(Ta + Xb, Tb);

        // pre-barrier: neighbor (for thread-exclusive) + wave total to LDS
        float pfa = __shfl_up(Fa, 1);
        float pfb = __shfl_up(Fb, 1);
        if (lane == 63) { tot[par][w][0] = Fa; tot[par][w][1] = Fb; }
        asm volatile("s_waitcnt lgkmcnt(0)" ::: "memory");
        asm volatile("s_barrier" ::: "memory");

        // all waves done reading sbuf[par] -> restage it with col j+2
        {
            int jn = j + 2; if (jn > txtL1) jn = txtL1;
            stage_col(cb + (size_t)jn * CSTR + (jn & ~3), &sbuf[par][0],
                      w, lane);
        }

        // cross-wave offset
        float Wxa = 0.0f, Wxb = NPAD;
        if (w >= 1) { Wxa = tot[par][0][0]; Wxb = tot[par][0][1]; }
        if (w >= 2) {
            float ga = tot[par][1][0], gb = tot[par][1][1];
            Wxb = lse2(ga + Wxb, gb);
            Wxa = ga + Wxa;
        }

        // thread-exclusive map (only beta needed downstream)
        float Exb;
        if (lane == 0) Exb = Wxb;
        else           Exb = lse2(pfa + Wxb, pfb);

        // finals: B_e = beta of (I_e o EX), EX applied to x_init=-inf
        float B0 = lse2(I0a + Exb, I0b);
        float B1 = lse2(I1a + Exb, I1b);
        float B2 = lse2(I2a + Exb, I2b);
        float B3 = lse2(I3a + Exb, I3b);

        if (j == txtL1 && tid == gtid) {
            float g = B0;
            if (gk == 1) g = B1;
            if (gk == 2) g = B2;
            if (gk == 3) g = B3;
            alpha_out[b] = g * scale;
        }

        A0 = B0; A1 = B1; A2 = B2; A3 = B3;
        par ^= 1;
    }
    asm volatile("s_waitcnt vmcnt(0)" ::: "memory");
}

// Kernel 3: loss = -mean_b alpha[b]
__global__ void finish_kernel(const float* __restrict__ alpha,
                              float* __restrict__ out) {
    float s = 0.f;
    #pragma unroll
    for (int b = 0; b < BB; ++b) s += alpha[b];
    out[0] = -(s / (float)BB);
}

extern "C" void kernel_launch(void* const* d_in, const int* in_sizes, int n_in,
                              void* d_out, int out_size, void* d_ws, size_t ws_size,
                              hipStream_t stream) {
    const float* mu_logvar    = (const float*)d_in[0];
    const float* melspec      = (const float*)d_in[1];
    const int*   text_lengths = (const int*)d_in[2];
    const int*   mel_lengths  = (const int*)d_in[3];
    float* out = (float*)d_out;

    float* alpha = (float*)d_ws;                 // 8 floats
    float* lpT   = (float*)d_ws + 64;            // 256B offset, [B][TXT_T][CSTR]

    lp_kernel<<<BB * TXT_T, 256, 0, stream>>>(mu_logvar, melspec, out + 1, lpT);
    scan_kernel<<<BB, NTHR, 0, stream>>>(lpT, text_lengths, mel_lengths, alpha);
    finish_kernel<<<1, 1, 0, stream>>>(alpha, out);
}